// Round 3
// baseline (138.703 us; speedup 1.0000x reference)
//
#include <hip/hip_runtime.h>

typedef float    v2f __attribute__((ext_vector_type(2)));
typedef _Float16 v2h __attribute__((ext_vector_type(2)));

__device__ __forceinline__ float fexp2(float x) { return __builtin_amdgcn_exp2f(x); }
__device__ __forceinline__ float flog2(float x) { return __builtin_amdgcn_logf(x); }
__device__ __forceinline__ float ffma (float a, float b, float c) { return __builtin_fmaf(a, b, c); }
__device__ __forceinline__ v2f  splat(float s) { v2f v; v.x = s; v.y = s; return v; }
__device__ __forceinline__ v2f  pkfma(v2f a, v2f b, v2f c) { return __builtin_elementwise_fma(a, b, c); }
__device__ __forceinline__ v2h  splath(float s) { v2h v; v.x = (_Float16)s; v.y = (_Float16)s; return v; }
__device__ __forceinline__ v2h  pkfmah(v2h a, v2h b, v2h c) { return __builtin_elementwise_fma(a, b, c); }
__device__ __forceinline__ v2h  cvt_pk(float a, float b) {
    return __builtin_bit_cast(v2h, __builtin_amdgcn_cvt_pkrtz(a, b));
}

#define LAB_EPS 0.008856f
#define F16_116 0.13793103448275862f   // 16/116
#define LOG2_10 3.3219280948873623f

// Module-scope folded-weight buffer (no d_ws dependence).
//   [0   .. 255]  float4 wsa[64]  : {w1_0j, w1_1j, w1_2j, b1_j}
//   [256 .. 511]  uint4  wsb[64]  : {pk(wp_j0), pk(wp_j1), pk(wp_j2), 0} half2-replicated
//   [512 .. 544]  epilogue consts : A[9], U[9], Wn[9] (= -w_logd),
//                                   bl2[3] (= log2(10)*b_logd), cv[3]
__device__ __align__(16) float g_ws[548];

// ---------------------------------------------------------------------------
// Prep kernel: 1 block x 64 threads. Folds all weights into g_ws so the main
// kernel reads them with wave-uniform (scalar) loads — no LDS, no staging.
// ---------------------------------------------------------------------------
__global__ __launch_bounds__(64) void prep_kernel(
    const float* __restrict__ w_seq1, const float* __restrict__ b_seq1,
    const float* __restrict__ w_seq2, const float* __restrict__ b_seq2,
    const float* __restrict__ w_lin,  const float* __restrict__ b_lin,
    const float* __restrict__ w_comb, const float* __restrict__ b_comb,
    const float* __restrict__ w_logd, const float* __restrict__ b_logd,
    const float* __restrict__ w_final,const float* __restrict__ b_final)
{
    const int j = threadIdx.x;           // 0..63
    float H3[9];
#pragma unroll
    for (int i = 0; i < 3; ++i)
#pragma unroll
        for (int c = 0; c < 3; ++c) {
            float h = 0.f;
            for (int m = 0; m < 3; ++m) h += w_comb[(i + 3) * 3 + m] * w_final[m * 3 + c];
            H3[i * 3 + c] = h;
        }

    float4* wsa = reinterpret_cast<float4*>(g_ws);
    uint4*  wsb = reinterpret_cast<uint4*>(g_ws) + 64;

    wsa[j] = make_float4(w_seq1[j], w_seq1[64 + j], w_seq1[128 + j], b_seq1[j]);
    const float w0 = w_seq2[j * 3 + 0], w1 = w_seq2[j * 3 + 1], w2 = w_seq2[j * 3 + 2];
    const float wp0 = w0 * H3[0] + w1 * H3[3] + w2 * H3[6];
    const float wp1 = w0 * H3[1] + w1 * H3[4] + w2 * H3[7];
    const float wp2 = w0 * H3[2] + w1 * H3[5] + w2 * H3[8];
    uint4 wb;
    wb.x = __builtin_bit_cast(unsigned, cvt_pk(wp0, wp0));
    wb.y = __builtin_bit_cast(unsigned, cvt_pk(wp1, wp1));
    wb.z = __builtin_bit_cast(unsigned, cvt_pk(wp2, wp2));
    wb.w = 0u;
    wsb[j] = wb;

    if (j == 0) {
        float* sm = g_ws + 512;
        float G[9], Wfb[9];
#pragma unroll
        for (int i = 0; i < 3; ++i)
#pragma unroll
            for (int c = 0; c < 3; ++c) {
                float gg = 0.f;
                for (int m = 0; m < 3; ++m) gg += w_comb[i * 3 + m] * w_final[m * 3 + c];
                G[i * 3 + c] = gg;
            }
#pragma unroll
        for (int k = 0; k < 3; ++k)
#pragma unroll
            for (int c = 0; c < 3; ++c) {
                float s = 0.f;
                for (int i = 0; i < 3; ++i) s += w_lin[k * 3 + i] * G[i * 3 + c];
                sm[k * 3 + c]      = s;                          // A
                Wfb[k * 3 + c]     = w_final[(k + 3) * 3 + c];
                sm[18 + k * 3 + c] = -w_logd[k * 3 + c];         // Wn = -w_logd
            }
#pragma unroll
        for (int c = 0; c < 3; ++c) {
            sm[9 + c]     = 500.0f * Wfb[3 + c];                                         // fX row
            sm[9 + 3 + c] = 116.0f * Wfb[c] - 500.0f * Wfb[3 + c] + 200.0f * Wfb[6 + c]; // fY row
            sm[9 + 6 + c] = -200.0f * Wfb[6 + c];                                        // fZ row
            float s = b_final[c] - 16.0f * Wfb[c];
            for (int i = 0; i < 3; ++i)
                s += b_lin[i] * G[i * 3 + c] + b_seq2[i] * H3[i * 3 + c]
                   + b_comb[i] * w_final[i * 3 + c];
            sm[27 + c] = LOG2_10 * b_logd[c];                    // bl2
            sm[30 + c] = s;                                      // cv
        }
    }
}

// ---------------------------------------------------------------------------
// Main kernel: P=4 points/thread, block=256 -> 2048 blocks = exactly 8
// blocks/CU (one residency round, no re-ramp). No LDS. Hidden-loop weights
// come from g_ws via s_load (SGPR broadcast); each j now feeds TWO
// independent packed-pair chains -> 2x ILP to hide s_load + dep latency.
// ---------------------------------------------------------------------------
__global__ __launch_bounds__(256) void fused_kernel(
    const float* __restrict__ x,
    float* __restrict__ out, int n)
{
    const float4* __restrict__ wsa = reinterpret_cast<const float4*>(g_ws);
    const uint4*  __restrict__ wsb = reinterpret_cast<const uint4*>(g_ws) + 64;
    const float*  __restrict__ wse = g_ws + 512;

    const int g = blockIdx.x * blockDim.x + threadIdx.x;
    if (g * 4 >= n) return;

    // 4 points = 12 floats = 3 float4 (coalesced 16B loads)
    const float4* xin = reinterpret_cast<const float4*>(x) + (size_t)g * 3;
    const float4 q0 = xin[0], q1 = xin[1], q2 = xin[2];
    // points: p0=(q0.x,q0.y,q0.z) p1=(q0.w,q1.x,q1.y) p2=(q1.z,q1.w,q2.x) p3=(q2.y,q2.z,q2.w)
    // pair 0 = {p0,p1}, pair 1 = {p2,p3}
    v2f xs[2][3];
    xs[0][0].x = q0.x; xs[0][0].y = q0.w;
    xs[0][1].x = q0.y; xs[0][1].y = q1.x;
    xs[0][2].x = q0.z; xs[0][2].y = q1.y;
    xs[1][0].x = q1.z; xs[1][0].y = q2.y;
    xs[1][1].x = q1.w; xs[1][1].y = q2.z;
    xs[1][2].x = q2.x; xs[1][2].y = q2.w;

    v2h acch[2][3];
#pragma unroll
    for (int q = 0; q < 2; ++q)
#pragma unroll
        for (int c = 0; c < 3; ++c) acch[q][c] = splath(0.f);

    // Hidden layer: t fp32 pk; tanh+acc packed f16.
    // tc = clamp(t,-3,3); u = tc^2; P cubic (max h-err ~0.02); h = tc*P.
#pragma unroll 4
    for (int j = 0; j < 64; ++j) {
        const float4 wa = wsa[j];
        const uint4  wb = wsb[j];
#pragma unroll
        for (int q = 0; q < 2; ++q) {
            v2f t = pkfma(xs[q][0], splat(wa.x),
                    pkfma(xs[q][1], splat(wa.y),
                    pkfma(xs[q][2], splat(wa.z), splat(wa.w))));
            v2h th = cvt_pk(t.x, t.y);
            th = __builtin_elementwise_min(__builtin_elementwise_max(th, splath(-3.0f)), splath(3.0f));
            const v2h u = th * th;
            v2h P = pkfmah(splath(-0.00120984f), u, splath(0.02603622f));
            P = pkfmah(P, u, splath(-0.20598500f));
            P = pkfmah(P, u, splath(0.95858467f));
            const v2h h = th * P;
            acch[q][0] = pkfmah(h, __builtin_bit_cast(v2h, wb.x), acch[q][0]);
            acch[q][1] = pkfmah(h, __builtin_bit_cast(v2h, wb.y), acch[q][1]);
            acch[q][2] = pkfmah(h, __builtin_bit_cast(v2h, wb.z), acch[q][2]);
        }
    }

    // Epilogue constants — uniform loads, land in SGPRs.
    float A[9], U[9], Wn[9], bl2[3], cv[3];
#pragma unroll
    for (int i = 0; i < 9; ++i) { A[i] = wse[i]; U[i] = wse[9 + i]; Wn[i] = wse[18 + i]; }
#pragma unroll
    for (int i = 0; i < 3; ++i) { bl2[i] = wse[27 + i]; cv[i] = wse[30 + i]; }

    float ov[12];
#pragma unroll
    for (int p = 0; p < 4; ++p) {
        const int q  = p >> 1;
        const int se = p & 1;
        const float L  = se ? xs[q][0].y : xs[q][0].x;
        const float aa = se ? xs[q][1].y : xs[q][1].x;
        const float bb = se ? xs[q][2].y : xs[q][2].x;
        const float a0 = se ? (float)acch[q][0].y : (float)acch[q][0].x;
        const float a1 = se ? (float)acch[q][1].y : (float)acch[q][1].x;
        const float a2 = se ? (float)acch[q][2].y : (float)acch[q][2].x;
        // ---- lab2rgb(x) ----
        const float fy = (L + 16.0f) * (1.0f / 116.0f);
        const float fx = ffma(aa,  0.002f, fy);
        const float fz = ffma(bb, -0.005f, fy);
        float rgb[3];
        {
            const float f3x = fx * fx * fx, f3y = fy * fy * fy, f3z = fz * fz * fz;
            const float tx = f3x > LAB_EPS ? f3x : (fx - F16_116) * (1.0f / 7.787f);
            const float ty = f3y > LAB_EPS ? f3y : (fy - F16_116) * (1.0f / 7.787f);
            const float tz = f3z > LAB_EPS ? f3z : (fz - F16_116) * (1.0f / 7.787f);
            const float X = tx * 0.95047f, Y = ty, Z = tz * 1.08883f;
            const float linv[3] = {
                 3.2404542f * X - 1.5371385f * Y - 0.4985314f * Z,
                -0.9692660f * X + 1.8760108f * Y + 0.0415560f * Z,
                 0.0556434f * X - 0.2040259f * Y + 1.0572252f * Z};
#pragma unroll
            for (int c = 0; c < 3; ++c) {
                const float cc = linv[c];
                const float lo = 12.92f * cc;
                const float hi = ffma(1.055f,
                                      fexp2(flog2(fmaxf(cc, 0.0031308f)) * (1.0f / 2.4f)),
                                      -0.055f);
                rgb[c] = cc <= 0.0031308f ? lo : hi;
            }
        }
        // ---- fused: -log10 -> @Wld+bld -> 10^ collapses to log2/exp2 domain ----
        // r10 = 10^(ld@Wld+bld) = exp2(lg@Wn + bl2),  lg = log2(rgb), Wn = -w_logd
        const float lg0 = flog2(rgb[0]);
        const float lg1 = flog2(rgb[1]);
        const float lg2 = flog2(rgb[2]);
        float lin2[3];
#pragma unroll
        for (int c = 0; c < 3; ++c) {
            const float e   = ffma(lg0, Wn[c], ffma(lg1, Wn[3 + c], ffma(lg2, Wn[6 + c], bl2[c])));
            const float r10 = fexp2(e);
            const float lo  = r10 * (1.0f / 12.92f);
            const float base = (fmaxf(r10, 0.04045f) + 0.055f) * (1.0f / 1.055f);
            const float hi  = fexp2(2.4f * flog2(base));
            lin2[c] = r10 <= 0.04045f ? lo : hi;
        }
        // ---- rgb2lab -> f-values ----
        const float X2 = (0.412453f * lin2[0] + 0.357580f * lin2[1] + 0.180423f * lin2[2]) * (1.0f / 0.95047f);
        const float Y2 =  0.212671f * lin2[0] + 0.715160f * lin2[1] + 0.072169f * lin2[2];
        const float Z2 = (0.019334f * lin2[0] + 0.119193f * lin2[1] + 0.950227f * lin2[2]) * (1.0f / 1.08883f);
        const float fX = X2 > LAB_EPS ? fexp2(flog2(fmaxf(X2, LAB_EPS)) * (1.0f / 3.0f)) : ffma(7.787f, X2, F16_116);
        const float fY = Y2 > LAB_EPS ? fexp2(flog2(fmaxf(Y2, LAB_EPS)) * (1.0f / 3.0f)) : ffma(7.787f, Y2, F16_116);
        const float fZ = Z2 > LAB_EPS ? fexp2(flog2(fmaxf(Z2, LAB_EPS)) * (1.0f / 3.0f)) : ffma(7.787f, Z2, F16_116);
        // ---- final combine (U-folded) ----
#pragma unroll
        for (int c = 0; c < 3; ++c) {
            float o = cv[c];
            o = ffma(L,  A[c],     o);
            o = ffma(aa, A[3 + c], o);
            o = ffma(bb, A[6 + c], o);
            o += (c == 0 ? a0 : (c == 1 ? a1 : a2));
            o = ffma(fX, U[c],     o);
            o = ffma(fY, U[3 + c], o);
            o = ffma(fZ, U[6 + c], o);
            ov[p * 3 + c] = o;
        }
    }

    float4* op = reinterpret_cast<float4*>(out) + (size_t)g * 3;
    op[0] = make_float4(ov[0], ov[1], ov[2],  ov[3]);
    op[1] = make_float4(ov[4], ov[5], ov[6],  ov[7]);
    op[2] = make_float4(ov[8], ov[9], ov[10], ov[11]);
}

extern "C" void kernel_launch(void* const* d_in, const int* in_sizes, int n_in,
                              void* d_out, int out_size, void* d_ws, size_t ws_size,
                              hipStream_t stream)
{
    const float* x       = (const float*)d_in[0];
    const float* w_seq1  = (const float*)d_in[1];
    const float* b_seq1  = (const float*)d_in[2];
    const float* w_seq2  = (const float*)d_in[3];
    const float* b_seq2  = (const float*)d_in[4];
    const float* w_lin   = (const float*)d_in[5];
    const float* b_lin   = (const float*)d_in[6];
    const float* w_comb  = (const float*)d_in[7];
    const float* b_comb  = (const float*)d_in[8];
    const float* w_logd  = (const float*)d_in[9];
    const float* b_logd  = (const float*)d_in[10];
    const float* w_final = (const float*)d_in[11];
    const float* b_final = (const float*)d_in[12];
    float* outp = (float*)d_out;

    const int n = in_sizes[0] / 3;            // 2,097,152 points
    const int threads = 256;
    const int total_threads = (n + 3) / 4;    // 4 points per thread
    const int blocks = (total_threads + threads - 1) / threads;

    prep_kernel<<<1, 64, 0, stream>>>(
        w_seq1, b_seq1, w_seq2, b_seq2, w_lin, b_lin, w_comb, b_comb,
        w_logd, b_logd, w_final, b_final);
    fused_kernel<<<blocks, threads, 0, stream>>>(x, outp, n);
}

// Round 4
// 138.148 us; speedup vs baseline: 1.0040x; 1.0040x over previous
//
#include <hip/hip_runtime.h>

typedef float    v2f __attribute__((ext_vector_type(2)));
typedef _Float16 v2h __attribute__((ext_vector_type(2)));

__device__ __forceinline__ float fexp2(float x) { return __builtin_amdgcn_exp2f(x); }
__device__ __forceinline__ float flog2(float x) { return __builtin_amdgcn_logf(x); }
__device__ __forceinline__ float ffma (float a, float b, float c) { return __builtin_fmaf(a, b, c); }
__device__ __forceinline__ v2f  splat(float s) { v2f v; v.x = s; v.y = s; return v; }
__device__ __forceinline__ v2f  pkfma(v2f a, v2f b, v2f c) { return __builtin_elementwise_fma(a, b, c); }
__device__ __forceinline__ v2h  splath(float s) { v2h v; v.x = (_Float16)s; v.y = (_Float16)s; return v; }
__device__ __forceinline__ v2h  pkfmah(v2h a, v2h b, v2h c) { return __builtin_elementwise_fma(a, b, c); }
__device__ __forceinline__ v2h  cvt_pk(float a, float b) {
    return __builtin_bit_cast(v2h, __builtin_amdgcn_cvt_pkrtz(a, b));
}

#define LAB_EPS 0.008856f
#define F16_116 0.13793103448275862f   // 16/116
#define LOG2_10 3.3219280948873623f

// Module-scope folded-weight buffer (no d_ws dependence).
//   [0   .. 255]  float4 wsa[64]  : {w1_0j, w1_1j, w1_2j, b1_j}
//   [256 .. 511]  uint4  wsb[64]  : {pk(wp_j0), pk(wp_j1), pk(wp_j2), 0} half2-replicated
//   [512 .. 544]  epilogue consts : A[9], U[9], Wn[9] (= -w_logd),
//                                   bl2[3] (= log2(10)*b_logd), cv[3]
__device__ __align__(16) float g_ws[548];

// ---------------------------------------------------------------------------
// Prep kernel: 1 block x 64 threads. Folds all weights into g_ws so the main
// kernel reads them with wave-uniform (scalar) loads — no LDS, no staging.
// ---------------------------------------------------------------------------
__global__ __launch_bounds__(64) void prep_kernel(
    const float* __restrict__ w_seq1, const float* __restrict__ b_seq1,
    const float* __restrict__ w_seq2, const float* __restrict__ b_seq2,
    const float* __restrict__ w_lin,  const float* __restrict__ b_lin,
    const float* __restrict__ w_comb, const float* __restrict__ b_comb,
    const float* __restrict__ w_logd, const float* __restrict__ b_logd,
    const float* __restrict__ w_final,const float* __restrict__ b_final)
{
    const int j = threadIdx.x;           // 0..63
    float H3[9];
#pragma unroll
    for (int i = 0; i < 3; ++i)
#pragma unroll
        for (int c = 0; c < 3; ++c) {
            float h = 0.f;
            for (int m = 0; m < 3; ++m) h += w_comb[(i + 3) * 3 + m] * w_final[m * 3 + c];
            H3[i * 3 + c] = h;
        }

    float4* wsa = reinterpret_cast<float4*>(g_ws);
    uint4*  wsb = reinterpret_cast<uint4*>(g_ws) + 64;

    wsa[j] = make_float4(w_seq1[j], w_seq1[64 + j], w_seq1[128 + j], b_seq1[j]);
    const float w0 = w_seq2[j * 3 + 0], w1 = w_seq2[j * 3 + 1], w2 = w_seq2[j * 3 + 2];
    const float wp0 = w0 * H3[0] + w1 * H3[3] + w2 * H3[6];
    const float wp1 = w0 * H3[1] + w1 * H3[4] + w2 * H3[7];
    const float wp2 = w0 * H3[2] + w1 * H3[5] + w2 * H3[8];
    uint4 wb;
    wb.x = __builtin_bit_cast(unsigned, cvt_pk(wp0, wp0));
    wb.y = __builtin_bit_cast(unsigned, cvt_pk(wp1, wp1));
    wb.z = __builtin_bit_cast(unsigned, cvt_pk(wp2, wp2));
    wb.w = 0u;
    wsb[j] = wb;

    if (j == 0) {
        float* sm = g_ws + 512;
        float G[9], Wfb[9];
#pragma unroll
        for (int i = 0; i < 3; ++i)
#pragma unroll
            for (int c = 0; c < 3; ++c) {
                float gg = 0.f;
                for (int m = 0; m < 3; ++m) gg += w_comb[i * 3 + m] * w_final[m * 3 + c];
                G[i * 3 + c] = gg;
            }
#pragma unroll
        for (int k = 0; k < 3; ++k)
#pragma unroll
            for (int c = 0; c < 3; ++c) {
                float s = 0.f;
                for (int i = 0; i < 3; ++i) s += w_lin[k * 3 + i] * G[i * 3 + c];
                sm[k * 3 + c]      = s;                          // A
                Wfb[k * 3 + c]     = w_final[(k + 3) * 3 + c];
                sm[18 + k * 3 + c] = -w_logd[k * 3 + c];         // Wn = -w_logd
            }
#pragma unroll
        for (int c = 0; c < 3; ++c) {
            sm[9 + c]     = 500.0f * Wfb[3 + c];                                         // fX row
            sm[9 + 3 + c] = 116.0f * Wfb[c] - 500.0f * Wfb[3 + c] + 200.0f * Wfb[6 + c]; // fY row
            sm[9 + 6 + c] = -200.0f * Wfb[6 + c];                                        // fZ row
            float s = b_final[c] - 16.0f * Wfb[c];
            for (int i = 0; i < 3; ++i)
                s += b_lin[i] * G[i * 3 + c] + b_seq2[i] * H3[i * 3 + c]
                   + b_comb[i] * w_final[i * 3 + c];
            sm[27 + c] = LOG2_10 * b_logd[c];                    // bl2
            sm[30 + c] = s;                                      // cv
        }
    }
}

// ---------------------------------------------------------------------------
// Main kernel: P=2 points/thread, block=256 -> 4096 blocks. No LDS.
// Hidden-loop weights via s_load (SGPR broadcast). Hidden loop is written
// STAGE-MAJOR over batches of 4 j's: all t's, all cvts, all clamps, all
// Horner stages, then the acc tail — forcing the register allocator to keep
// 4 independent dep-chains live (VGPR ~28 -> ~70) so latency is hidden
// in-wave instead of exposed (r3 diagnosis: 40% stall at VGPR=28).
// __launch_bounds__(256,5): allow up to ~102 VGPR, keep >=5 waves/SIMD.
// ---------------------------------------------------------------------------
__global__ __launch_bounds__(256, 5) void fused_kernel(
    const float* __restrict__ x,
    float* __restrict__ out, int n)
{
    const float4* __restrict__ wsa = reinterpret_cast<const float4*>(g_ws);
    const uint4*  __restrict__ wsb = reinterpret_cast<const uint4*>(g_ws) + 64;
    const float*  __restrict__ wse = g_ws + 512;

    const int g = blockIdx.x * blockDim.x + threadIdx.x;
    if (g * 2 >= n) return;

    // 2 points = 6 floats = 3 float2 (coalesced 8B loads)
    const float2* xin = reinterpret_cast<const float2*>(x) + (size_t)g * 3;
    const float2 v0 = xin[0], v1 = xin[1], v2 = xin[2];
    // p0 = {v0.x, v0.y, v1.x}, p1 = {v1.y, v2.x, v2.y}
    v2f xs2[3];
    xs2[0].x = v0.x; xs2[0].y = v1.y;
    xs2[1].x = v0.y; xs2[1].y = v2.x;
    xs2[2].x = v1.x; xs2[2].y = v2.y;

    v2h acc0 = splath(0.f), acc1 = splath(0.f), acc2 = splath(0.f);

    // Hidden layer, stage-major 4-wide batches.
    // tc = clamp(t,-3,3); u = tc^2; P cubic (max h-err ~0.02); h = tc*P.
#pragma unroll 2
    for (int j0 = 0; j0 < 64; j0 += 4) {
        float4 wa0 = wsa[j0 + 0], wa1 = wsa[j0 + 1], wa2 = wsa[j0 + 2], wa3 = wsa[j0 + 3];
        uint4  wb0 = wsb[j0 + 0], wb1 = wsb[j0 + 1], wb2 = wsb[j0 + 2], wb3 = wsb[j0 + 3];

        v2f t0 = pkfma(xs2[0], splat(wa0.x), pkfma(xs2[1], splat(wa0.y), pkfma(xs2[2], splat(wa0.z), splat(wa0.w))));
        v2f t1 = pkfma(xs2[0], splat(wa1.x), pkfma(xs2[1], splat(wa1.y), pkfma(xs2[2], splat(wa1.z), splat(wa1.w))));
        v2f t2 = pkfma(xs2[0], splat(wa2.x), pkfma(xs2[1], splat(wa2.y), pkfma(xs2[2], splat(wa2.z), splat(wa2.w))));
        v2f t3 = pkfma(xs2[0], splat(wa3.x), pkfma(xs2[1], splat(wa3.y), pkfma(xs2[2], splat(wa3.z), splat(wa3.w))));

        v2h th0 = cvt_pk(t0.x, t0.y);
        v2h th1 = cvt_pk(t1.x, t1.y);
        v2h th2 = cvt_pk(t2.x, t2.y);
        v2h th3 = cvt_pk(t3.x, t3.y);

        const v2h hi3 = splath(3.0f), lo3 = splath(-3.0f);
        th0 = __builtin_elementwise_min(__builtin_elementwise_max(th0, lo3), hi3);
        th1 = __builtin_elementwise_min(__builtin_elementwise_max(th1, lo3), hi3);
        th2 = __builtin_elementwise_min(__builtin_elementwise_max(th2, lo3), hi3);
        th3 = __builtin_elementwise_min(__builtin_elementwise_max(th3, lo3), hi3);

        v2h u0 = th0 * th0, u1 = th1 * th1, u2 = th2 * th2, u3 = th3 * th3;

        const v2h c3 = splath(-0.00120984f), c2 = splath(0.02603622f);
        const v2h c1 = splath(-0.20598500f), c0 = splath(0.95858467f);
        v2h P0 = pkfmah(c3, u0, c2);
        v2h P1 = pkfmah(c3, u1, c2);
        v2h P2 = pkfmah(c3, u2, c2);
        v2h P3 = pkfmah(c3, u3, c2);
        P0 = pkfmah(P0, u0, c1);
        P1 = pkfmah(P1, u1, c1);
        P2 = pkfmah(P2, u2, c1);
        P3 = pkfmah(P3, u3, c1);
        P0 = pkfmah(P0, u0, c0);
        P1 = pkfmah(P1, u1, c0);
        P2 = pkfmah(P2, u2, c0);
        P3 = pkfmah(P3, u3, c0);

        v2h h0 = th0 * P0, h1 = th1 * P1, h2 = th2 * P2, h3 = th3 * P3;

        acc0 = pkfmah(h0, __builtin_bit_cast(v2h, wb0.x), acc0);
        acc1 = pkfmah(h0, __builtin_bit_cast(v2h, wb0.y), acc1);
        acc2 = pkfmah(h0, __builtin_bit_cast(v2h, wb0.z), acc2);
        acc0 = pkfmah(h1, __builtin_bit_cast(v2h, wb1.x), acc0);
        acc1 = pkfmah(h1, __builtin_bit_cast(v2h, wb1.y), acc1);
        acc2 = pkfmah(h1, __builtin_bit_cast(v2h, wb1.z), acc2);
        acc0 = pkfmah(h2, __builtin_bit_cast(v2h, wb2.x), acc0);
        acc1 = pkfmah(h2, __builtin_bit_cast(v2h, wb2.y), acc1);
        acc2 = pkfmah(h2, __builtin_bit_cast(v2h, wb2.z), acc2);
        acc0 = pkfmah(h3, __builtin_bit_cast(v2h, wb3.x), acc0);
        acc1 = pkfmah(h3, __builtin_bit_cast(v2h, wb3.y), acc1);
        acc2 = pkfmah(h3, __builtin_bit_cast(v2h, wb3.z), acc2);
    }

    // Epilogue constants — uniform loads, land in SGPRs.
    float A[9], U[9], Wn[9], bl2[3], cv[3];
#pragma unroll
    for (int i = 0; i < 9; ++i) { A[i] = wse[i]; U[i] = wse[9 + i]; Wn[i] = wse[18 + i]; }
#pragma unroll
    for (int i = 0; i < 3; ++i) { bl2[i] = wse[27 + i]; cv[i] = wse[30 + i]; }

    float ov[6];
#pragma unroll
    for (int p = 0; p < 2; ++p) {
        const float L  = p ? xs2[0].y : xs2[0].x;
        const float aa = p ? xs2[1].y : xs2[1].x;
        const float bb = p ? xs2[2].y : xs2[2].x;
        const float a0 = p ? (float)acc0.y : (float)acc0.x;
        const float a1 = p ? (float)acc1.y : (float)acc1.x;
        const float a2 = p ? (float)acc2.y : (float)acc2.x;
        // ---- lab2rgb(x) ----
        const float fy = (L + 16.0f) * (1.0f / 116.0f);
        const float fx = ffma(aa,  0.002f, fy);
        const float fz = ffma(bb, -0.005f, fy);
        float rgb[3];
        {
            const float f3x = fx * fx * fx, f3y = fy * fy * fy, f3z = fz * fz * fz;
            const float tx = f3x > LAB_EPS ? f3x : (fx - F16_116) * (1.0f / 7.787f);
            const float ty = f3y > LAB_EPS ? f3y : (fy - F16_116) * (1.0f / 7.787f);
            const float tz = f3z > LAB_EPS ? f3z : (fz - F16_116) * (1.0f / 7.787f);
            const float X = tx * 0.95047f, Y = ty, Z = tz * 1.08883f;
            const float linv[3] = {
                 3.2404542f * X - 1.5371385f * Y - 0.4985314f * Z,
                -0.9692660f * X + 1.8760108f * Y + 0.0415560f * Z,
                 0.0556434f * X - 0.2040259f * Y + 1.0572252f * Z};
#pragma unroll
            for (int c = 0; c < 3; ++c) {
                const float cc = linv[c];
                const float lo = 12.92f * cc;
                const float hi = ffma(1.055f,
                                      fexp2(flog2(fmaxf(cc, 0.0031308f)) * (1.0f / 2.4f)),
                                      -0.055f);
                rgb[c] = cc <= 0.0031308f ? lo : hi;
            }
        }
        // ---- fused: -log10 -> @Wld+bld -> 10^ collapses to log2/exp2 domain ----
        // r10 = 10^(ld@Wld+bld) = exp2(lg@Wn + bl2),  lg = log2(rgb), Wn = -w_logd
        const float lg0 = flog2(rgb[0]);
        const float lg1 = flog2(rgb[1]);
        const float lg2 = flog2(rgb[2]);
        float lin2[3];
#pragma unroll
        for (int c = 0; c < 3; ++c) {
            const float e   = ffma(lg0, Wn[c], ffma(lg1, Wn[3 + c], ffma(lg2, Wn[6 + c], bl2[c])));
            const float r10 = fexp2(e);
            const float lo  = r10 * (1.0f / 12.92f);
            const float base = (fmaxf(r10, 0.04045f) + 0.055f) * (1.0f / 1.055f);
            const float hi  = fexp2(2.4f * flog2(base));
            lin2[c] = r10 <= 0.04045f ? lo : hi;
        }
        // ---- rgb2lab -> f-values ----
        const float X2 = (0.412453f * lin2[0] + 0.357580f * lin2[1] + 0.180423f * lin2[2]) * (1.0f / 0.95047f);
        const float Y2 =  0.212671f * lin2[0] + 0.715160f * lin2[1] + 0.072169f * lin2[2];
        const float Z2 = (0.019334f * lin2[0] + 0.119193f * lin2[1] + 0.950227f * lin2[2]) * (1.0f / 1.08883f);
        const float fX = X2 > LAB_EPS ? fexp2(flog2(fmaxf(X2, LAB_EPS)) * (1.0f / 3.0f)) : ffma(7.787f, X2, F16_116);
        const float fY = Y2 > LAB_EPS ? fexp2(flog2(fmaxf(Y2, LAB_EPS)) * (1.0f / 3.0f)) : ffma(7.787f, Y2, F16_116);
        const float fZ = Z2 > LAB_EPS ? fexp2(flog2(fmaxf(Z2, LAB_EPS)) * (1.0f / 3.0f)) : ffma(7.787f, Z2, F16_116);
        // ---- final combine (U-folded) ----
#pragma unroll
        for (int c = 0; c < 3; ++c) {
            float o = cv[c];
            o = ffma(L,  A[c],     o);
            o = ffma(aa, A[3 + c], o);
            o = ffma(bb, A[6 + c], o);
            o += (c == 0 ? a0 : (c == 1 ? a1 : a2));
            o = ffma(fX, U[c],     o);
            o = ffma(fY, U[3 + c], o);
            o = ffma(fZ, U[6 + c], o);
            ov[p * 3 + c] = o;
        }
    }

    float2* op = reinterpret_cast<float2*>(out) + (size_t)g * 3;
    op[0] = make_float2(ov[0], ov[1]);
    op[1] = make_float2(ov[2], ov[3]);
    op[2] = make_float2(ov[4], ov[5]);
}

extern "C" void kernel_launch(void* const* d_in, const int* in_sizes, int n_in,
                              void* d_out, int out_size, void* d_ws, size_t ws_size,
                              hipStream_t stream)
{
    const float* x       = (const float*)d_in[0];
    const float* w_seq1  = (const float*)d_in[1];
    const float* b_seq1  = (const float*)d_in[2];
    const float* w_seq2  = (const float*)d_in[3];
    const float* b_seq2  = (const float*)d_in[4];
    const float* w_lin   = (const float*)d_in[5];
    const float* b_lin   = (const float*)d_in[6];
    const float* w_comb  = (const float*)d_in[7];
    const float* b_comb  = (const float*)d_in[8];
    const float* w_logd  = (const float*)d_in[9];
    const float* b_logd  = (const float*)d_in[10];
    const float* w_final = (const float*)d_in[11];
    const float* b_final = (const float*)d_in[12];
    float* outp = (float*)d_out;

    const int n = in_sizes[0] / 3;            // 2,097,152 points
    const int threads = 256;
    const int total_threads = (n + 1) / 2;    // 2 points per thread
    const int blocks = (total_threads + threads - 1) / threads;

    prep_kernel<<<1, 64, 0, stream>>>(
        w_seq1, b_seq1, w_seq2, b_seq2, w_lin, b_lin, w_comb, b_comb,
        w_logd, b_logd, w_final, b_final);
    fused_kernel<<<blocks, threads, 0, stream>>>(x, outp, n);
}

// Round 6
// 133.075 us; speedup vs baseline: 1.0423x; 1.0381x over previous
//
#include <hip/hip_runtime.h>

typedef float    v2f __attribute__((ext_vector_type(2)));
typedef _Float16 v2h __attribute__((ext_vector_type(2)));

__device__ __forceinline__ float fexp2(float x) { return __builtin_amdgcn_exp2f(x); }
__device__ __forceinline__ float flog2(float x) { return __builtin_amdgcn_logf(x); }
__device__ __forceinline__ float ffma (float a, float b, float c) { return __builtin_fmaf(a, b, c); }
__device__ __forceinline__ v2f  splat(float s) { v2f v; v.x = s; v.y = s; return v; }
__device__ __forceinline__ v2f  pkfma(v2f a, v2f b, v2f c) { return __builtin_elementwise_fma(a, b, c); }
__device__ __forceinline__ v2h  splath(float s) { v2h v; v.x = (_Float16)s; v.y = (_Float16)s; return v; }
__device__ __forceinline__ v2h  pkfmah(v2h a, v2h b, v2h c) { return __builtin_elementwise_fma(a, b, c); }
__device__ __forceinline__ v2h  cvt_pk(float a, float b) {
    return __builtin_bit_cast(v2h, __builtin_amdgcn_cvt_pkrtz(a, b));
}
// packed-pair helpers (elementwise on the two points; halves are separate VGPRs,
// so per-element selects are plain cmp+cndmask — no pack/unpack cost)
__device__ __forceinline__ v2f pexp2(v2f e) { v2f r; r.x = fexp2(e.x); r.y = fexp2(e.y); return r; }
__device__ __forceinline__ v2f plog2(v2f e) { v2f r; r.x = flog2(e.x); r.y = flog2(e.y); return r; }
__device__ __forceinline__ v2f selgt(v2f c, float thr, v2f a, v2f b) {
    v2f r; r.x = c.x > thr ? a.x : b.x; r.y = c.y > thr ? a.y : b.y; return r;
}
__device__ __forceinline__ v2f selle(v2f c, float thr, v2f a, v2f b) {
    v2f r; r.x = c.x <= thr ? a.x : b.x; r.y = c.y <= thr ? a.y : b.y; return r;
}
__device__ __forceinline__ v2f pmax(v2f a, float s) { return __builtin_elementwise_max(a, splat(s)); }

#define LAB_EPS 0.008856f
#define F16_116 0.13793103448275862f   // 16/116
#define LOG2_10 3.3219280948873623f

// ---------------------------------------------------------------------------
// Single kernel (r0 structure) — the separate prep launch cost ~5-7us at
// harness level (r0 vs r2/r4 comparison), eating the dispatch win.
//  - wsa needs NO fold: read raw w_seq1/b_seq1 as float4 with loop-uniform
//    indices -> s_load SGPR broadcast (zero DS, zero prologue work).
//  - only wsb (w_seq2 @ H3, needs FP fold) + 33 epilogue consts use a 1.2KB
//    LDS prologue; hidden loop does 64 broadcast ds_read_b128 (batched 4-ahead
//    by the stage-major structure so lgkm latency hides).
//  - epilogue linear algebra packed as v2f over the 2 points (trans stays
//    scalar). Numerics identical to r2/r4 (passed).
// ---------------------------------------------------------------------------
__global__ __launch_bounds__(256) void fused_kernel(
    const float* __restrict__ x,
    const float* __restrict__ w_seq1, const float* __restrict__ b_seq1,
    const float* __restrict__ w_seq2, const float* __restrict__ b_seq2,
    const float* __restrict__ w_lin,  const float* __restrict__ b_lin,
    const float* __restrict__ w_comb, const float* __restrict__ b_comb,
    const float* __restrict__ w_logd, const float* __restrict__ b_logd,
    const float* __restrict__ w_final,const float* __restrict__ b_final,
    float* __restrict__ out, int n)
{
    __shared__ uint4 wsbL[64];    // j: {pk(w2p_j0), pk(w2p_j1), pk(w2p_j2), 0} half2-replicated
    __shared__ float smlds[33];   // A[9], U[9], Wn[9], bl2[3], cv[3]

    const int tid = threadIdx.x;
    if (tid < 64) {
        const int j = tid;
        float H3[9];
#pragma unroll
        for (int i = 0; i < 3; ++i)
#pragma unroll
            for (int c = 0; c < 3; ++c) {
                float h = 0.f;
                for (int m = 0; m < 3; ++m) h += w_comb[(i + 3) * 3 + m] * w_final[m * 3 + c];
                H3[i * 3 + c] = h;
            }
        const float w0 = w_seq2[j * 3 + 0], w1 = w_seq2[j * 3 + 1], w2 = w_seq2[j * 3 + 2];
        const float wp0 = w0 * H3[0] + w1 * H3[3] + w2 * H3[6];
        const float wp1 = w0 * H3[1] + w1 * H3[4] + w2 * H3[7];
        const float wp2 = w0 * H3[2] + w1 * H3[5] + w2 * H3[8];
        uint4 wb;
        wb.x = __builtin_bit_cast(unsigned, cvt_pk(wp0, wp0));
        wb.y = __builtin_bit_cast(unsigned, cvt_pk(wp1, wp1));
        wb.z = __builtin_bit_cast(unsigned, cvt_pk(wp2, wp2));
        wb.w = 0u;
        wsbL[j] = wb;
        if (j == 0) {
            float G[9], Wfb[9];
#pragma unroll
            for (int i = 0; i < 3; ++i)
#pragma unroll
                for (int c = 0; c < 3; ++c) {
                    float gg = 0.f;
                    for (int m = 0; m < 3; ++m) gg += w_comb[i * 3 + m] * w_final[m * 3 + c];
                    G[i * 3 + c] = gg;
                }
#pragma unroll
            for (int k = 0; k < 3; ++k)
#pragma unroll
                for (int c = 0; c < 3; ++c) {
                    float s = 0.f;
                    for (int i = 0; i < 3; ++i) s += w_lin[k * 3 + i] * G[i * 3 + c];
                    smlds[k * 3 + c]      = s;                      // A
                    Wfb[k * 3 + c]        = w_final[(k + 3) * 3 + c];
                    smlds[18 + k * 3 + c] = -w_logd[k * 3 + c];     // Wn = -w_logd
                }
#pragma unroll
            for (int c = 0; c < 3; ++c) {
                smlds[9 + c]     = 500.0f * Wfb[3 + c];                                         // fX row
                smlds[9 + 3 + c] = 116.0f * Wfb[c] - 500.0f * Wfb[3 + c] + 200.0f * Wfb[6 + c]; // fY row
                smlds[9 + 6 + c] = -200.0f * Wfb[6 + c];                                        // fZ row
                float s = b_final[c] - 16.0f * Wfb[c];
                for (int i = 0; i < 3; ++i)
                    s += b_lin[i] * G[i * 3 + c] + b_seq2[i] * H3[i * 3 + c]
                       + b_comb[i] * w_final[i * 3 + c];
                smlds[27 + c] = LOG2_10 * b_logd[c];                // bl2
                smlds[30 + c] = s;                                  // cv
            }
        }
    }
    __syncthreads();

    const int g = blockIdx.x * blockDim.x + tid;
    if (g * 2 >= n) return;

    // 2 points = 6 floats = 3 float2 (coalesced 8B loads)
    const float2* xin = reinterpret_cast<const float2*>(x) + (size_t)g * 3;
    const float2 v0 = xin[0], v1 = xin[1], v2 = xin[2];
    // p0 = {v0.x, v0.y, v1.x}, p1 = {v1.y, v2.x, v2.y}
    v2f xs2[3];
    xs2[0].x = v0.x; xs2[0].y = v1.y;
    xs2[1].x = v0.y; xs2[1].y = v2.x;
    xs2[2].x = v1.x; xs2[2].y = v2.y;

    v2h acc0 = splath(0.f), acc1 = splath(0.f), acc2 = splath(0.f);

    // w_seq1 rows are contiguous in j: row i at float4 offset i*16 + j/4.
    const float4* __restrict__ w1v = reinterpret_cast<const float4*>(w_seq1);
    const float4* __restrict__ b1v = reinterpret_cast<const float4*>(b_seq1);

    // Hidden layer, stage-major 4-wide batches; weights via s_load (uniform),
    // wsb via broadcast ds_read_b128 batched 4-ahead.
#pragma unroll 2
    for (int j0 = 0; j0 < 64; j0 += 4) {
        const int q = j0 >> 2;
        const float4 wr0 = w1v[q];         // w_seq1[0][j0..j0+3]
        const float4 wr1 = w1v[16 + q];    // w_seq1[1][...]
        const float4 wr2 = w1v[32 + q];    // w_seq1[2][...]
        const float4 wrb = b1v[q];         // b_seq1[...]
        const uint4 wb0 = wsbL[j0 + 0], wb1 = wsbL[j0 + 1], wb2 = wsbL[j0 + 2], wb3 = wsbL[j0 + 3];

        v2f t0 = pkfma(xs2[0], splat(wr0.x), pkfma(xs2[1], splat(wr1.x), pkfma(xs2[2], splat(wr2.x), splat(wrb.x))));
        v2f t1 = pkfma(xs2[0], splat(wr0.y), pkfma(xs2[1], splat(wr1.y), pkfma(xs2[2], splat(wr2.y), splat(wrb.y))));
        v2f t2 = pkfma(xs2[0], splat(wr0.z), pkfma(xs2[1], splat(wr1.z), pkfma(xs2[2], splat(wr2.z), splat(wrb.z))));
        v2f t3 = pkfma(xs2[0], splat(wr0.w), pkfma(xs2[1], splat(wr1.w), pkfma(xs2[2], splat(wr2.w), splat(wrb.w))));

        v2h th0 = cvt_pk(t0.x, t0.y);
        v2h th1 = cvt_pk(t1.x, t1.y);
        v2h th2 = cvt_pk(t2.x, t2.y);
        v2h th3 = cvt_pk(t3.x, t3.y);

        const v2h hi3 = splath(3.0f), lo3 = splath(-3.0f);
        th0 = __builtin_elementwise_min(__builtin_elementwise_max(th0, lo3), hi3);
        th1 = __builtin_elementwise_min(__builtin_elementwise_max(th1, lo3), hi3);
        th2 = __builtin_elementwise_min(__builtin_elementwise_max(th2, lo3), hi3);
        th3 = __builtin_elementwise_min(__builtin_elementwise_max(th3, lo3), hi3);

        v2h u0 = th0 * th0, u1 = th1 * th1, u2 = th2 * th2, u3 = th3 * th3;

        const v2h c3 = splath(-0.00120984f), c2 = splath(0.02603622f);
        const v2h c1 = splath(-0.20598500f), c0 = splath(0.95858467f);
        v2h P0 = pkfmah(c3, u0, c2);
        v2h P1 = pkfmah(c3, u1, c2);
        v2h P2 = pkfmah(c3, u2, c2);
        v2h P3 = pkfmah(c3, u3, c2);
        P0 = pkfmah(P0, u0, c1);
        P1 = pkfmah(P1, u1, c1);
        P2 = pkfmah(P2, u2, c1);
        P3 = pkfmah(P3, u3, c1);
        P0 = pkfmah(P0, u0, c0);
        P1 = pkfmah(P1, u1, c0);
        P2 = pkfmah(P2, u2, c0);
        P3 = pkfmah(P3, u3, c0);

        v2h h0 = th0 * P0, h1 = th1 * P1, h2 = th2 * P2, h3 = th3 * P3;

        acc0 = pkfmah(h0, __builtin_bit_cast(v2h, wb0.x), acc0);
        acc1 = pkfmah(h0, __builtin_bit_cast(v2h, wb0.y), acc1);
        acc2 = pkfmah(h0, __builtin_bit_cast(v2h, wb0.z), acc2);
        acc0 = pkfmah(h1, __builtin_bit_cast(v2h, wb1.x), acc0);
        acc1 = pkfmah(h1, __builtin_bit_cast(v2h, wb1.y), acc1);
        acc2 = pkfmah(h1, __builtin_bit_cast(v2h, wb1.z), acc2);
        acc0 = pkfmah(h2, __builtin_bit_cast(v2h, wb2.x), acc0);
        acc1 = pkfmah(h2, __builtin_bit_cast(v2h, wb2.y), acc1);
        acc2 = pkfmah(h2, __builtin_bit_cast(v2h, wb2.z), acc2);
        acc0 = pkfmah(h3, __builtin_bit_cast(v2h, wb3.x), acc0);
        acc1 = pkfmah(h3, __builtin_bit_cast(v2h, wb3.y), acc1);
        acc2 = pkfmah(h3, __builtin_bit_cast(v2h, wb3.z), acc2);
    }

    // Epilogue constants from LDS (broadcast reads, once).
    float A[9], U[9], Wn[9], bl2[3], cv[3];
#pragma unroll
    for (int i = 0; i < 9; ++i) { A[i] = smlds[i]; U[i] = smlds[9 + i]; Wn[i] = smlds[18 + i]; }
#pragma unroll
    for (int i = 0; i < 3; ++i) { bl2[i] = smlds[27 + i]; cv[i] = smlds[30 + i]; }

    // ---- Epilogue, packed over the 2 points (v2f = {p0, p1}) ----
    v2f sq0, sq1, sq2;
    sq0.x = (float)acc0.x; sq0.y = (float)acc0.y;
    sq1.x = (float)acc1.x; sq1.y = (float)acc1.y;
    sq2.x = (float)acc2.x; sq2.y = (float)acc2.y;

    // lab2rgb(x)
    const v2f fy = (xs2[0] + splat(16.0f)) * splat(1.0f / 116.0f);
    const v2f fx = pkfma(xs2[1], splat( 0.002f), fy);
    const v2f fz = pkfma(xs2[2], splat(-0.005f), fy);
    const v2f f3x = fx * fx * fx, f3y = fy * fy * fy, f3z = fz * fz * fz;
    const v2f tx = selgt(f3x, LAB_EPS, f3x, (fx - splat(F16_116)) * splat(1.0f / 7.787f));
    const v2f ty = selgt(f3y, LAB_EPS, f3y, (fy - splat(F16_116)) * splat(1.0f / 7.787f));
    const v2f tz = selgt(f3z, LAB_EPS, f3z, (fz - splat(F16_116)) * splat(1.0f / 7.787f));
    const v2f X = tx * splat(0.95047f), Y = ty, Z = tz * splat(1.08883f);
    v2f linv[3];
    linv[0] = pkfma(X, splat( 3.2404542f), pkfma(Y, splat(-1.5371385f), Z * splat(-0.4985314f)));
    linv[1] = pkfma(X, splat(-0.9692660f), pkfma(Y, splat( 1.8760108f), Z * splat( 0.0415560f)));
    linv[2] = pkfma(X, splat( 0.0556434f), pkfma(Y, splat(-0.2040259f), Z * splat( 1.0572252f)));
    v2f lg[3];
#pragma unroll
    for (int c = 0; c < 3; ++c) {
        const v2f cc = linv[c];
        const v2f lo = cc * splat(12.92f);
        const v2f hi = pkfma(pexp2(plog2(pmax(cc, 0.0031308f)) * splat(1.0f / 2.4f)),
                             splat(1.055f), splat(-0.055f));
        lg[c] = plog2(selle(cc, 0.0031308f, lo, hi));
    }
    // r10 = exp2(lg@Wn + bl2); srgb_to_linear(r10)
    v2f lin2[3];
#pragma unroll
    for (int c = 0; c < 3; ++c) {
        const v2f e   = pkfma(lg[0], splat(Wn[c]),
                        pkfma(lg[1], splat(Wn[3 + c]),
                        pkfma(lg[2], splat(Wn[6 + c]), splat(bl2[c]))));
        const v2f r10 = pexp2(e);
        const v2f lo  = r10 * splat(1.0f / 12.92f);
        const v2f base = (pmax(r10, 0.04045f) + splat(0.055f)) * splat(1.0f / 1.055f);
        const v2f hi  = pexp2(plog2(base) * splat(2.4f));
        lin2[c] = selle(r10, 0.04045f, lo, hi);
    }
    // rgb2lab -> f-values
    const v2f X2 = pkfma(lin2[0], splat(0.412453f), pkfma(lin2[1], splat(0.357580f), lin2[2] * splat(0.180423f))) * splat(1.0f / 0.95047f);
    const v2f Y2 = pkfma(lin2[0], splat(0.212671f), pkfma(lin2[1], splat(0.715160f), lin2[2] * splat(0.072169f)));
    const v2f Z2 = pkfma(lin2[0], splat(0.019334f), pkfma(lin2[1], splat(0.119193f), lin2[2] * splat(0.950227f))) * splat(1.0f / 1.08883f);
    const v2f fX = selgt(X2, LAB_EPS, pexp2(plog2(pmax(X2, LAB_EPS)) * splat(1.0f / 3.0f)), pkfma(X2, splat(7.787f), splat(F16_116)));
    const v2f fY = selgt(Y2, LAB_EPS, pexp2(plog2(pmax(Y2, LAB_EPS)) * splat(1.0f / 3.0f)), pkfma(Y2, splat(7.787f), splat(F16_116)));
    const v2f fZ = selgt(Z2, LAB_EPS, pexp2(plog2(pmax(Z2, LAB_EPS)) * splat(1.0f / 3.0f)), pkfma(Z2, splat(7.787f), splat(F16_116)));
    // final combine (U-folded)
    v2f o[3];
#pragma unroll
    for (int c = 0; c < 3; ++c) {
        v2f oc = splat(cv[c]);
        oc = pkfma(xs2[0], splat(A[c]),     oc);
        oc = pkfma(xs2[1], splat(A[3 + c]), oc);
        oc = pkfma(xs2[2], splat(A[6 + c]), oc);
        oc = oc + (c == 0 ? sq0 : (c == 1 ? sq1 : sq2));
        oc = pkfma(fX, splat(U[c]),     oc);
        oc = pkfma(fY, splat(U[3 + c]), oc);
        oc = pkfma(fZ, splat(U[6 + c]), oc);
        o[c] = oc;
    }

    float2* op = reinterpret_cast<float2*>(out) + (size_t)g * 3;
    op[0] = make_float2(o[0].x, o[1].x);
    op[1] = make_float2(o[2].x, o[0].y);
    op[2] = make_float2(o[1].y, o[2].y);
}

extern "C" void kernel_launch(void* const* d_in, const int* in_sizes, int n_in,
                              void* d_out, int out_size, void* d_ws, size_t ws_size,
                              hipStream_t stream)
{
    const float* x       = (const float*)d_in[0];
    const float* w_seq1  = (const float*)d_in[1];
    const float* b_seq1  = (const float*)d_in[2];
    const float* w_seq2  = (const float*)d_in[3];
    const float* b_seq2  = (const float*)d_in[4];
    const float* w_lin   = (const float*)d_in[5];
    const float* b_lin   = (const float*)d_in[6];
    const float* w_comb  = (const float*)d_in[7];
    const float* b_comb  = (const float*)d_in[8];
    const float* w_logd  = (const float*)d_in[9];
    const float* b_logd  = (const float*)d_in[10];
    const float* w_final = (const float*)d_in[11];
    const float* b_final = (const float*)d_in[12];
    float* outp = (float*)d_out;

    const int n = in_sizes[0] / 3;            // 2,097,152 points
    const int threads = 256;
    const int total_threads = (n + 1) / 2;    // 2 points per thread
    const int blocks = (total_threads + threads - 1) / threads;

    fused_kernel<<<blocks, threads, 0, stream>>>(
        x, w_seq1, b_seq1, w_seq2, b_seq2, w_lin, b_lin, w_comb, b_comb,
        w_logd, b_logd, w_final, b_final, outp, n);
}